// Round 4
// baseline (410.094 us; speedup 1.0000x reference)
//
#include <hip/hip_runtime.h>
#include <hip/hip_bf16.h>
#include <stdint.h>

#define E_ 8
#define H_ 1024
#define I_ 2816
#define T_ 512

typedef __attribute__((ext_vector_type(4))) float f32x4;
typedef __attribute__((ext_vector_type(8))) short short8;

__device__ __forceinline__ unsigned short f2bf(float f) {   // RNE (for x, h)
    return __builtin_bit_cast(unsigned short, __float2bfloat16(f));
}
// weights hold e4m3 values exactly representable in bf16 -> truncation is exact
__device__ __forceinline__ uint32_t pack_trunc(float lo, float hi) {
    return (__builtin_bit_cast(uint32_t, hi) & 0xFFFF0000u) |
           (__builtin_bit_cast(uint32_t, lo) >> 16);
}

// ---------------- routing: counts + bucket (single block) ----------------
__global__ __launch_bounds__(512) void routek(const int* __restrict__ idx,
                                              int* __restrict__ counts,
                                              int* __restrict__ bucket) {
    int tid = threadIdx.x;
    if (tid < E_) counts[tid] = 0;
    for (int i = tid; i < E_ * T_; i += 512) bucket[i] = 0;
    __syncthreads();
    int e = idx[tid];
    int pos = atomicAdd(counts + e, 1);
    bucket[e * T_ + pos] = tid;
}

// -------- GEMM1: tile 128 tok x 64 feat, BK=128; h = silu(g)*u --------
__global__ __launch_bounds__(256) void gemm1(const float* __restrict__ x,
                                             const float* __restrict__ wgu,
                                             const float* __restrict__ sgu_p,
                                             const int* __restrict__ counts,
                                             const int* __restrict__ bucket,
                                             __hip_bfloat16* __restrict__ hbuf) {
    int e = blockIdx.x >> 2, m = blockIdx.x & 3;
    int cnt = counts[e];
    if (m * 128 >= cnt) return;
    int f0 = blockIdx.y * 64;

    __shared__ char smem[64 * 1024];
    char* sA = smem;               // 128 rows x 256B (bf16 x-tile), swizzled
    char* sG = smem + 32 * 1024;   // 64 x 256B gate
    char* sU = smem + 48 * 1024;   // 64 x 256B up
    __shared__ int tok[128];

    int tid = threadIdx.x;
    if (tid < 128) tok[tid] = bucket[e * T_ + m * 128 + tid];

    int wv = tid >> 6, lane = tid & 63;
    const float sgu = sgu_p[0];
    const float* wg_base = wgu + (size_t)e * (2 * (size_t)I_ * H_);

    f32x4 accg[2][4], accu[2][4];
#pragma unroll
    for (int mi = 0; mi < 2; mi++)
#pragma unroll
        for (int n = 0; n < 4; n++) { accg[mi][n] = (f32x4){0,0,0,0}; accu[mi][n] = (f32x4){0,0,0,0}; }

    for (int k0 = 0; k0 < H_; k0 += 128) {
        __syncthreads();
        // A: 128 rows x 16 chunks (8 f32 -> 8 bf16 RNE)
        for (int c = tid; c < 128 * 16; c += 256) {
            int row = c >> 4, ch = c & 15;
            const float4* xp = (const float4*)(x + (size_t)tok[row] * H_ + k0 + ch * 8);
            float4 a = xp[0], b = xp[1];
            union { unsigned short us[8]; uint4 v; } o;
            o.us[0] = f2bf(a.x); o.us[1] = f2bf(a.y); o.us[2] = f2bf(a.z); o.us[3] = f2bf(a.w);
            o.us[4] = f2bf(b.x); o.us[5] = f2bf(b.y); o.us[6] = f2bf(b.z); o.us[7] = f2bf(b.w);
            *(uint4*)(sA + ((row * 256 + ch * 16) ^ ((row & 15) << 4))) = o.v;
        }
        // B: gate+up, 2 x 64 rows x 16 chunks (8 f32 -> 8 bf16 exact trunc)
        for (int c = tid; c < 2048; c += 256) {
            int t2 = c >> 10, cc = c & 1023;
            int row = cc >> 4, ch = cc & 15;
            const float4* wp = (const float4*)(wg_base + ((size_t)(t2 ? I_ + f0 : f0) + row) * H_ + k0 + ch * 8);
            float4 a = wp[0], b = wp[1];
            uint4 o = make_uint4(pack_trunc(a.x, a.y), pack_trunc(a.z, a.w),
                                 pack_trunc(b.x, b.y), pack_trunc(b.z, b.w));
            *(uint4*)((t2 ? sU : sG) + ((row * 256 + ch * 16) ^ ((row & 15) << 4))) = o;
        }
        __syncthreads();
        int r = lane & 15, kg = lane >> 4;
#pragma unroll
        for (int kk = 0; kk < 4; kk++) {
            short8 av[2];
#pragma unroll
            for (int mi = 0; mi < 2; mi++) {
                int arow = wv * 32 + mi * 16 + r;
                av[mi] = *(short8*)(sA + ((arow * 256 + kk * 64 + kg * 16) ^ ((arow & 15) << 4)));
            }
#pragma unroll
            for (int n = 0; n < 4; n++) {
                int brow = n * 16 + r;
                int off = (brow * 256 + kk * 64 + kg * 16) ^ ((brow & 15) << 4);
                short8 bg = *(short8*)(sG + off);
                short8 bu = *(short8*)(sU + off);
#pragma unroll
                for (int mi = 0; mi < 2; mi++) {
                    accg[mi][n] = __builtin_amdgcn_mfma_f32_16x16x32_bf16(av[mi], bg, accg[mi][n], 0, 0, 0);
                    accu[mi][n] = __builtin_amdgcn_mfma_f32_16x16x32_bf16(av[mi], bu, accu[mi][n], 0, 0, 0);
                }
            }
        }
    }
    int r = lane & 15, q = lane >> 4;
#pragma unroll
    for (int mi = 0; mi < 2; mi++)
#pragma unroll
        for (int n = 0; n < 4; n++)
#pragma unroll
            for (int j = 0; j < 4; j++) {
                int rowInTile = wv * 32 + mi * 16 + q * 4 + j;
                int pos = m * 128 + rowInTile;
                if (pos < cnt) {
                    int t = tok[rowInTile];
                    float g = accg[mi][n][j] * sgu;
                    float u = accu[mi][n][j] * sgu;
                    float hv = (g / (1.f + __expf(-g))) * u;
                    hbuf[(size_t)t * I_ + f0 + n * 16 + r] = __float2bfloat16(hv);
                }
            }
}

// -------- GEMM2: tile 128 tok x 32 hcols, BK=128 over I --------
__global__ __launch_bounds__(256) void gemm2(const __hip_bfloat16* __restrict__ hbuf,
                                             const float* __restrict__ wd,
                                             const float* __restrict__ sd_p,
                                             const int* __restrict__ counts,
                                             const int* __restrict__ bucket,
                                             float* __restrict__ out) {
    int e = blockIdx.x >> 2, m = blockIdx.x & 3;
    int cnt = counts[e];
    if (m * 128 >= cnt) return;
    int h0 = blockIdx.y * 32;

    __shared__ char smem[40 * 1024];
    char* sA = smem;               // 128 x 256B (h tile bf16)
    char* sB = smem + 32 * 1024;   // 32 x 256B (w_d tile bf16)
    __shared__ int tok[128];

    int tid = threadIdx.x;
    if (tid < 128) tok[tid] = bucket[e * T_ + m * 128 + tid];

    int wv = tid >> 6, lane = tid & 63;
    const float sd = sd_p[0];
    const float* wd_base = wd + (size_t)e * ((size_t)H_ * I_);

    f32x4 acc[2][2];
#pragma unroll
    for (int mi = 0; mi < 2; mi++)
#pragma unroll
        for (int n = 0; n < 2; n++) acc[mi][n] = (f32x4){0,0,0,0};

    for (int k0 = 0; k0 < I_; k0 += 128) {
        __syncthreads();
        // A: 128 rows x 16 chunks of 16B (bf16 direct copy)
        for (int c = tid; c < 2048; c += 256) {
            int row = c >> 4, ch = c & 15;
            uint4 v = *(const uint4*)((const unsigned short*)hbuf + (size_t)tok[row] * I_ + k0 + ch * 8);
            *(uint4*)(sA + ((row * 256 + ch * 16) ^ ((row & 15) << 4))) = v;
        }
        // B: 32 rows x 16 chunks (8 f32 -> 8 bf16 trunc)
        for (int c = tid; c < 512; c += 256) {
            int row = c >> 4, ch = c & 15;
            const float4* wp = (const float4*)(wd_base + (size_t)(h0 + row) * I_ + k0 + ch * 8);
            float4 a = wp[0], b = wp[1];
            uint4 o = make_uint4(pack_trunc(a.x, a.y), pack_trunc(a.z, a.w),
                                 pack_trunc(b.x, b.y), pack_trunc(b.z, b.w));
            *(uint4*)(sB + ((row * 256 + ch * 16) ^ ((row & 15) << 4))) = o;
        }
        __syncthreads();
        int r = lane & 15, kg = lane >> 4;
#pragma unroll
        for (int kk = 0; kk < 4; kk++) {
            short8 av[2];
#pragma unroll
            for (int mi = 0; mi < 2; mi++) {
                int arow = wv * 32 + mi * 16 + r;
                av[mi] = *(short8*)(sA + ((arow * 256 + kk * 64 + kg * 16) ^ ((arow & 15) << 4)));
            }
#pragma unroll
            for (int n = 0; n < 2; n++) {
                int brow = n * 16 + r;
                int off = (brow * 256 + kk * 64 + kg * 16) ^ ((brow & 15) << 4);
                short8 b = *(short8*)(sB + off);
#pragma unroll
                for (int mi = 0; mi < 2; mi++)
                    acc[mi][n] = __builtin_amdgcn_mfma_f32_16x16x32_bf16(av[mi], b, acc[mi][n], 0, 0, 0);
            }
        }
    }
    int r = lane & 15, q = lane >> 4;
#pragma unroll
    for (int mi = 0; mi < 2; mi++)
#pragma unroll
        for (int n = 0; n < 2; n++)
#pragma unroll
            for (int j = 0; j < 4; j++) {
                int rowInTile = wv * 32 + mi * 16 + q * 4 + j;
                int pos = m * 128 + rowInTile;
                if (pos < cnt) {
                    int t = tok[rowInTile];
                    out[(size_t)t * H_ + h0 + n * 16 + r] = acc[mi][n][j] * sd;
                }
            }
}

extern "C" void kernel_launch(void* const* d_in, const int* in_sizes, int n_in,
                              void* d_out, int out_size, void* d_ws, size_t ws_size,
                              hipStream_t stream) {
    const float* x    = (const float*)d_in[0];
    const int*   eidx = (const int*)d_in[1];
    const float* wgu  = (const float*)d_in[2];   // fp8 values stored as f32
    const float* sgu  = (const float*)d_in[3];
    const float* wd   = (const float*)d_in[4];   // fp8 values stored as f32
    const float* sd   = (const float*)d_in[5];
    float* out = (float*)d_out;

    char* ws = (char*)d_ws;
    int* counts = (int*)ws;                                  // 32 B
    int* bucket = (int*)(ws + 1024);                         // 16 KB
    __hip_bfloat16* hbuf = (__hip_bfloat16*)(ws + 32768);    // 2.88 MB

    routek<<<1, 512, 0, stream>>>(eidx, counts, bucket);
    gemm1<<<dim3(E_ * 4, I_ / 64), 256, 0, stream>>>(x, wgu, sgu, counts, bucket, hbuf);
    gemm2<<<dim3(E_ * 4, H_ / 32), 256, 0, stream>>>(hbuf, wd, sd, counts, bucket, out);
}

// Round 5
// 351.693 us; speedup vs baseline: 1.1661x; 1.1661x over previous
//
#include <hip/hip_runtime.h>
#include <hip/hip_bf16.h>
#include <stdint.h>

#define E_ 8
#define H_ 1024
#define I_ 2816
#define T_ 512

typedef __attribute__((ext_vector_type(4))) float f32x4;
typedef __attribute__((ext_vector_type(8))) short short8;

struct F8 { float4 a, b; };

__device__ __forceinline__ F8 ldf8(const float* p) {
    F8 r; r.a = *(const float4*)p; r.b = *(const float4*)(p + 4); return r;
}
__device__ __forceinline__ unsigned short f2bf(float f) {   // RNE (x, h)
    return __builtin_bit_cast(unsigned short, __float2bfloat16(f));
}
// weights hold exact e4m3 values -> bf16 truncation is exact
__device__ __forceinline__ uint32_t pack_trunc(float lo, float hi) {
    return (__builtin_bit_cast(uint32_t, hi) & 0xFFFF0000u) |
           (__builtin_bit_cast(uint32_t, lo) >> 16);
}
__device__ __forceinline__ short8 cvtB(const F8& v) {
    uint4 o = make_uint4(pack_trunc(v.a.x, v.a.y), pack_trunc(v.a.z, v.a.w),
                         pack_trunc(v.b.x, v.b.y), pack_trunc(v.b.z, v.b.w));
    return __builtin_bit_cast(short8, o);
}

// ---------------- routing ----------------
__global__ __launch_bounds__(512) void routek(const int* __restrict__ idx,
                                              int* __restrict__ counts,
                                              int* __restrict__ bucket) {
    int tid = threadIdx.x;
    if (tid < E_) counts[tid] = 0;
    for (int i = tid; i < E_ * T_; i += 512) bucket[i] = 0;
    __syncthreads();
    int e = idx[tid];
    int pos = atomicAdd(counts + e, 1);
    bucket[e * T_ + pos] = tid;
}

// ---- GEMM1: 128 tok x 64 f (4 waves x 16 rows, gate+up streamed to regs) ----
__global__ __launch_bounds__(256) void gemm1(const float* __restrict__ x,
                                             const float* __restrict__ wgu,
                                             const float* __restrict__ sgu_p,
                                             const int* __restrict__ counts,
                                             const int* __restrict__ bucket,
                                             __hip_bfloat16* __restrict__ hbuf) {
    int e = blockIdx.x >> 2, m = blockIdx.x & 3;
    int cnt = counts[e];
    if (m * 128 >= cnt) return;
    int f0 = blockIdx.y * 64;

    __shared__ char sA[64 * 1024];   // 128 tok x 256 k bf16 (512B rows, swizzled)
    __shared__ int tok[128];

    int tid = threadIdx.x;
    if (tid < 128) tok[tid] = bucket[e * T_ + m * 128 + tid];
    int w = tid >> 6, lane = tid & 63;
    int r16 = lane & 15, kg = lane >> 4;
    const float sgu = sgu_p[0];

    const float* gp = wgu + (size_t)e * (2 * (size_t)I_ * H_) +
                      (size_t)(f0 + w * 16 + r16) * H_ + kg * 8;
    const float* up = gp + (size_t)I_ * H_;

    f32x4 accg[8], accu[8];
#pragma unroll
    for (int mi = 0; mi < 8; mi++) { accg[mi] = (f32x4){0,0,0,0}; accu[mi] = (f32x4){0,0,0,0}; }

    F8 bg0 = {}, bu0 = {}, bg1 = {}, bu1 = {};
    __syncthreads();   // tok visible

    for (int c = 0; c < 4; ++c) {
        int k0 = c * 256;
        if (c) __syncthreads();    // previous chunk compute done
        // stage A chunk: 128 rows x 512B, f32 -> bf16 RNE
        for (int cc = tid; cc < 4096; cc += 256) {
            int row = cc >> 5, ch = cc & 31;
            const float* xp = x + (size_t)tok[row] * H_ + k0 + ch * 8;
            float4 a = *(const float4*)xp, b = *(const float4*)(xp + 4);
            union { unsigned short us[8]; uint4 v; } o;
            o.us[0] = f2bf(a.x); o.us[1] = f2bf(a.y); o.us[2] = f2bf(a.z); o.us[3] = f2bf(a.w);
            o.us[4] = f2bf(b.x); o.us[5] = f2bf(b.y); o.us[6] = f2bf(b.z); o.us[7] = f2bf(b.w);
            *(uint4*)(sA + ((row * 512 + ch * 16) ^ ((row & 15) << 4))) = o.v;
        }
        __syncthreads();
        if (c == 0) { bg0 = ldf8(gp); bu0 = ldf8(up); }   // prologue ks=0
#pragma unroll
        for (int kk = 0; kk < 8; kk += 2) {
            int ks = c * 8 + kk;
            if (ks + 1 < 32) { bg1 = ldf8(gp + (size_t)(ks + 1) * 32); bu1 = ldf8(up + (size_t)(ks + 1) * 32); }
            {   // compute slot 0 at kk
                short8 Bg = cvtB(bg0), Bu = cvtB(bu0);
#pragma unroll
                for (int mi = 0; mi < 8; ++mi) {
                    int row = mi * 16 + r16;
                    short8 a = *(short8*)(sA + ((row * 512 + kk * 64 + kg * 16) ^ ((r16) << 4)));
                    accg[mi] = __builtin_amdgcn_mfma_f32_16x16x32_bf16(a, Bg, accg[mi], 0, 0, 0);
                    accu[mi] = __builtin_amdgcn_mfma_f32_16x16x32_bf16(a, Bu, accu[mi], 0, 0, 0);
                }
            }
            if (ks + 2 < 32) { bg0 = ldf8(gp + (size_t)(ks + 2) * 32); bu0 = ldf8(up + (size_t)(ks + 2) * 32); }
            {   // compute slot 1 at kk+1
                short8 Bg = cvtB(bg1), Bu = cvtB(bu1);
#pragma unroll
                for (int mi = 0; mi < 8; ++mi) {
                    int row = mi * 16 + r16;
                    short8 a = *(short8*)(sA + ((row * 512 + (kk + 1) * 64 + kg * 16) ^ ((r16) << 4)));
                    accg[mi] = __builtin_amdgcn_mfma_f32_16x16x32_bf16(a, Bg, accg[mi], 0, 0, 0);
                    accu[mi] = __builtin_amdgcn_mfma_f32_16x16x32_bf16(a, Bu, accu[mi], 0, 0, 0);
                }
            }
        }
    }
    // epilogue: h = silu(g)*u, col = f0 + w*16 + r16
#pragma unroll
    for (int mi = 0; mi < 8; ++mi)
#pragma unroll
        for (int j = 0; j < 4; ++j) {
            int rowInTile = mi * 16 + kg * 4 + j;
            int pos = m * 128 + rowInTile;
            if (pos < cnt) {
                int t = tok[rowInTile];
                float g = accg[mi][j] * sgu;
                float u = accu[mi][j] * sgu;
                float hv = (g / (1.f + __expf(-g))) * u;
                hbuf[(size_t)t * I_ + f0 + w * 16 + r16] = __float2bfloat16(hv);
            }
        }
}

// ---- GEMM2: no LDS. 128 tok x 32 h-cols (2 waves x 16), A gathered from L2 ----
__global__ __launch_bounds__(128) void gemm2(const __hip_bfloat16* __restrict__ hbuf,
                                             const float* __restrict__ wd,
                                             const float* __restrict__ sd_p,
                                             const int* __restrict__ counts,
                                             const int* __restrict__ bucket,
                                             float* __restrict__ out) {
    int e = blockIdx.x >> 2, m = blockIdx.x & 3;
    int cnt = counts[e];
    if (m * 128 >= cnt) return;
    int h0 = blockIdx.y * 32;

    __shared__ int tok[128];
    int tid = threadIdx.x;
    if (tid < 128) tok[tid] = bucket[e * T_ + m * 128 + tid];
    __syncthreads();

    int w = tid >> 6, lane = tid & 63;
    int r16 = lane & 15, kg = lane >> 4;
    const float sd = sd_p[0];

    const float* bp = wd + (size_t)e * ((size_t)H_ * I_) +
                      (size_t)(h0 + w * 16 + r16) * I_ + kg * 8;
    const unsigned short* ap[8];
#pragma unroll
    for (int mi = 0; mi < 8; ++mi)
        ap[mi] = (const unsigned short*)hbuf + (size_t)tok[mi * 16 + r16] * I_ + kg * 8;

    f32x4 acc[8];
#pragma unroll
    for (int mi = 0; mi < 8; mi++) acc[mi] = (f32x4){0,0,0,0};

    F8 b0 = {}, b1 = {};
    uint4 a0[8], a1[8];
    b0 = ldf8(bp);
#pragma unroll
    for (int mi = 0; mi < 8; ++mi) a0[mi] = *(const uint4*)(ap[mi]);

    for (int ks = 0; ks < 88; ks += 2) {
        if (ks + 1 < 88) {
            b1 = ldf8(bp + (size_t)(ks + 1) * 32);
#pragma unroll
            for (int mi = 0; mi < 8; ++mi) a1[mi] = *(const uint4*)(ap[mi] + (size_t)(ks + 1) * 32);
        }
        {
            short8 B = cvtB(b0);
#pragma unroll
            for (int mi = 0; mi < 8; ++mi)
                acc[mi] = __builtin_amdgcn_mfma_f32_16x16x32_bf16(__builtin_bit_cast(short8, a0[mi]), B, acc[mi], 0, 0, 0);
        }
        if (ks + 2 < 88) {
            b0 = ldf8(bp + (size_t)(ks + 2) * 32);
#pragma unroll
            for (int mi = 0; mi < 8; ++mi) a0[mi] = *(const uint4*)(ap[mi] + (size_t)(ks + 2) * 32);
        }
        {
            short8 B = cvtB(b1);
#pragma unroll
            for (int mi = 0; mi < 8; ++mi)
                acc[mi] = __builtin_amdgcn_mfma_f32_16x16x32_bf16(__builtin_bit_cast(short8, a1[mi]), B, acc[mi], 0, 0, 0);
        }
    }

#pragma unroll
    for (int mi = 0; mi < 8; ++mi)
#pragma unroll
        for (int j = 0; j < 4; ++j) {
            int rowInTile = mi * 16 + kg * 4 + j;
            int pos = m * 128 + rowInTile;
            if (pos < cnt) {
                int t = tok[rowInTile];
                out[(size_t)t * H_ + h0 + w * 16 + r16] = acc[mi][j] * sd;
            }
        }
}

extern "C" void kernel_launch(void* const* d_in, const int* in_sizes, int n_in,
                              void* d_out, int out_size, void* d_ws, size_t ws_size,
                              hipStream_t stream) {
    const float* x    = (const float*)d_in[0];
    const int*   eidx = (const int*)d_in[1];
    const float* wgu  = (const float*)d_in[2];   // fp8 values stored as f32
    const float* sgu  = (const float*)d_in[3];
    const float* wd   = (const float*)d_in[4];   // fp8 values stored as f32
    const float* sd   = (const float*)d_in[5];
    float* out = (float*)d_out;

    char* ws = (char*)d_ws;
    int* counts = (int*)ws;                                  // 32 B
    int* bucket = (int*)(ws + 1024);                         // 16 KB
    __hip_bfloat16* hbuf = (__hip_bfloat16*)(ws + 32768);    // 2.88 MB

    routek<<<1, 512, 0, stream>>>(eidx, counts, bucket);
    gemm1<<<dim3(E_ * 4, I_ / 64), 256, 0, stream>>>(x, wgu, sgu, counts, bucket, hbuf);
    gemm2<<<dim3(E_ * 4, H_ / 32), 128, 0, stream>>>(hbuf, wd, sd, counts, bucket, out);
}

// Round 6
// 123.956 us; speedup vs baseline: 3.3084x; 2.8372x over previous
//
#include <hip/hip_runtime.h>
#include <hip/hip_bf16.h>
#include <stdint.h>

#define E_ 8
#define H_ 1024
#define I_ 2816
#define T_ 512

typedef __attribute__((ext_vector_type(4))) float f32x4;
typedef __attribute__((ext_vector_type(8))) short short8;

typedef __attribute__((address_space(1))) const unsigned GAS;
typedef __attribute__((address_space(3))) unsigned LAS;

__device__ __forceinline__ void dma16(const void* g, void* l) {
    __builtin_amdgcn_global_load_lds((GAS*)g, (LAS*)l, 16, 0, 0);
}
__device__ __forceinline__ unsigned short f2bf(float f) {   // RNE (x)
    return __builtin_bit_cast(unsigned short, __float2bfloat16(f));
}
__device__ __forceinline__ uint32_t pack_rne(float lo, float hi) {
    return (uint32_t)f2bf(lo) | ((uint32_t)f2bf(hi) << 16);
}
// weights hold exact e4m3 values -> bf16 truncation is exact
__device__ __forceinline__ uint32_t pack_trunc(float lo, float hi) {
    return (__builtin_bit_cast(uint32_t, hi) & 0xFFFF0000u) |
           (__builtin_bit_cast(uint32_t, lo) >> 16);
}

// ---------------- routing ----------------
__global__ __launch_bounds__(512) void routek(const int* __restrict__ idx,
                                              int* __restrict__ counts,
                                              int* __restrict__ bucket) {
    int tid = threadIdx.x;
    if (tid < E_) counts[tid] = 0;
    for (int i = tid; i < E_ * T_; i += 512) bucket[i] = 0;
    __syncthreads();
    int e = idx[tid];
    int pos = atomicAdd(counts + e, 1);
    bucket[e * T_ + pos] = tid;
}

// ---- GEMM1: 64 tok x 32 feat (32 gate + 32 up rows), BK=64 f32, 16 steps ----
// LDS: A(bf16) dbuf 2x8KB @0 ; B(f32) dbuf 2x16KB @16KB ; tok @48KB
__global__ __launch_bounds__(256) void gemm1(const float* __restrict__ x,
                                             const float* __restrict__ wgu,
                                             const float* __restrict__ sgu_p,
                                             const int* __restrict__ counts,
                                             const int* __restrict__ bucket,
                                             __hip_bfloat16* __restrict__ hbuf) {
    int e = blockIdx.x >> 1, mt = blockIdx.x & 1;
    int cnt = counts[e];
    if (mt * 64 >= cnt) return;
    int f0 = blockIdx.y * 32;

    __shared__ __align__(16) char smem[48 * 1024 + 256];
    int* tok = (int*)(smem + 48 * 1024);

    int tid = threadIdx.x;
    int w = tid >> 6, lane = tid & 63;
    int r16 = lane & 15, kg = lane >> 4;

    // B-DMA setup: 64 rows (32 gate + 32 up) x 256B/step; pre-swizzled source
    const char* wg_e = (const char*)(wgu + (size_t)e * 2 * (size_t)I_ * H_);
    const char* srcB[4];
    char* dstB[4];
#pragma unroll
    for (int i = 0; i < 4; ++i) {
        int U = (w * 4 + i) * 64 + lane;         // 16B-unit index in tile
        int row = U >> 4, slot = U & 15;
        int wr = (row < 32) ? (f0 + row) : (I_ + f0 + row - 32);
        srcB[i] = wg_e + (size_t)wr * 4096 + (size_t)((slot ^ (row & 15)) * 16);
        dstB[i] = smem + 16 * 1024 + (w * 4 + i) * 1024;
    }
#pragma unroll
    for (int i = 0; i < 4; ++i) dma16(srcB[i], dstB[i]);   // step 0 B

    if (tid < 64) tok[tid] = bucket[e * T_ + mt * 64 + tid];
    __syncthreads();

    // A staging (reg->cvt->LDS): row=tid>>2, part=tid&3 (16 f32 each)
    int arow = tid >> 2, apart = tid & 3;
    const float* srcA = x + (size_t)tok[arow] * H_ + apart * 16;
    int awoff0 = (arow * 128 + apart * 32) ^ ((arow & 7) << 4);
    int awoff1 = (arow * 128 + apart * 32 + 16) ^ ((arow & 7) << 4);
    {
        float4 a0 = *(const float4*)(srcA), a1 = *(const float4*)(srcA + 4);
        float4 a2 = *(const float4*)(srcA + 8), a3 = *(const float4*)(srcA + 12);
        uint4 o0 = make_uint4(pack_rne(a0.x, a0.y), pack_rne(a0.z, a0.w),
                              pack_rne(a1.x, a1.y), pack_rne(a1.z, a1.w));
        uint4 o1 = make_uint4(pack_rne(a2.x, a2.y), pack_rne(a2.z, a2.w),
                              pack_rne(a3.x, a3.y), pack_rne(a3.z, a3.w));
        *(uint4*)(smem + awoff0) = o0;
        *(uint4*)(smem + awoff1) = o1;
    }
    __syncthreads();   // buf0 ready (drains B-DMA too)

    f32x4 acc[4];
#pragma unroll
    for (int m = 0; m < 4; ++m) acc[m] = (f32x4){0, 0, 0, 0};
    const float sgu = sgu_p[0];

    for (int t = 0; t < 16; ++t) {
        int cur = t & 1;
        char* Ab = smem + cur * 8192;
        char* Bb = smem + 16384 + cur * 16384;
        float4 pa0, pa1, pa2, pa3;
        if (t < 15) {
            int ns = cur ^ 1;
#pragma unroll
            for (int i = 0; i < 4; ++i)
                dma16(srcB[i] + (size_t)(t + 1) * 256, dstB[i] + ns * 16384);
            const float* s = srcA + (size_t)(t + 1) * 64;
            pa0 = *(const float4*)(s);      pa1 = *(const float4*)(s + 4);
            pa2 = *(const float4*)(s + 8);  pa3 = *(const float4*)(s + 12);
        }
#pragma unroll
        for (int kk = 0; kk < 2; ++kk) {
            int brow = w * 16 + r16;
            int bo = brow * 256 + kk * 128 + kg * 32;
            int sw = (brow & 15) << 4;
            float4 b0 = *(float4*)(Bb + (bo ^ sw));
            float4 b1 = *(float4*)(Bb + ((bo + 16) ^ sw));
            uint4 bu = make_uint4(pack_trunc(b0.x, b0.y), pack_trunc(b0.z, b0.w),
                                  pack_trunc(b1.x, b1.y), pack_trunc(b1.z, b1.w));
            short8 B = __builtin_bit_cast(short8, bu);
#pragma unroll
            for (int m = 0; m < 4; ++m) {
                int ar = m * 16 + r16;
                short8 A = *(short8*)(Ab + ((ar * 128 + kk * 64 + kg * 16) ^ ((ar & 7) << 4)));
                acc[m] = __builtin_amdgcn_mfma_f32_16x16x32_bf16(A, B, acc[m], 0, 0, 0);
            }
        }
        if (t < 15) {
            char* An = smem + (cur ^ 1) * 8192;
            uint4 o0 = make_uint4(pack_rne(pa0.x, pa0.y), pack_rne(pa0.z, pa0.w),
                                  pack_rne(pa1.x, pa1.y), pack_rne(pa1.z, pa1.w));
            uint4 o1 = make_uint4(pack_rne(pa2.x, pa2.y), pack_rne(pa2.z, pa2.w),
                                  pack_rne(pa3.x, pa3.y), pack_rne(pa3.z, pa3.w));
            *(uint4*)(An + awoff0) = o0;
            *(uint4*)(An + awoff1) = o1;
        }
        __syncthreads();
    }

    // epilogue: waves 2,3 (up) export u*s via LDS; waves 0,1 (gate) fuse silu
    float* ex = (float*)smem;
    if (w >= 2) {
        float* dst = ex + (w - 2) * 1024;
#pragma unroll
        for (int m = 0; m < 4; ++m)
#pragma unroll
            for (int j = 0; j < 4; ++j)
                dst[(m * 16 + kg * 4 + j) * 16 + r16] = acc[m][j] * sgu;
    }
    __syncthreads();
    if (w < 2) {
        const float* src = ex + w * 1024;
#pragma unroll
        for (int m = 0; m < 4; ++m)
#pragma unroll
            for (int j = 0; j < 4; ++j) {
                int tr = m * 16 + kg * 4 + j;
                int pos = mt * 64 + tr;
                if (pos < cnt) {
                    float g = acc[m][j] * sgu;
                    float u = src[tr * 16 + r16];
                    float hv = (g / (1.f + __expf(-g))) * u;
                    hbuf[(size_t)tok[tr] * I_ + f0 + w * 16 + r16] = __float2bfloat16(hv);
                }
            }
    }
}

// ---- GEMM2: 64 tok x 16 hcols, BK=128, 22 steps; all-DMA staging ----
// LDS: A(bf16) dbuf 2x16KB @0 ; B(f32) dbuf 2x8KB @32KB ; tok @48KB
__global__ __launch_bounds__(256) void gemm2(const __hip_bfloat16* __restrict__ hbuf,
                                             const float* __restrict__ wd,
                                             const float* __restrict__ sd_p,
                                             const int* __restrict__ counts,
                                             const int* __restrict__ bucket,
                                             float* __restrict__ out) {
    int e = blockIdx.x >> 1, mt = blockIdx.x & 1;
    int cnt = counts[e];
    if (mt * 64 >= cnt) return;
    int h0 = blockIdx.y * 16;

    __shared__ __align__(16) char smem[48 * 1024 + 256];
    int* tok = (int*)(smem + 48 * 1024);
    int tid = threadIdx.x;
    int w = tid >> 6, lane = tid & 63;
    int r16 = lane & 15, kg = lane >> 4;

    if (tid < 64) tok[tid] = bucket[e * T_ + mt * 64 + tid];
    __syncthreads();

    const char* hb = (const char*)hbuf;
    const char* srcA[4]; char* dstA[4];
#pragma unroll
    for (int i = 0; i < 4; ++i) {
        int U = (w * 4 + i) * 64 + lane;
        int row = U >> 4, slot = U & 15;
        srcA[i] = hb + ((size_t)tok[row] * I_) * 2 + (size_t)((slot ^ (row & 15)) * 16);
        dstA[i] = smem + (w * 4 + i) * 1024;
    }
    const char* wd_e = (const char*)(wd + (size_t)e * (size_t)H_ * I_);
    const char* srcB[2]; char* dstB[2];
#pragma unroll
    for (int i = 0; i < 2; ++i) {
        int U = (w * 2 + i) * 64 + lane;
        int row = U >> 5, slot = U & 31;
        srcB[i] = wd_e + (size_t)(h0 + row) * ((size_t)I_ * 4) + (size_t)((slot ^ (row & 15)) * 16);
        dstB[i] = smem + 32 * 1024 + (w * 2 + i) * 1024;
    }
#pragma unroll
    for (int i = 0; i < 4; ++i) dma16(srcA[i], dstA[i]);
#pragma unroll
    for (int i = 0; i < 2; ++i) dma16(srcB[i], dstB[i]);
    __syncthreads();

    f32x4 acc = (f32x4){0, 0, 0, 0};
    const float sd = sd_p[0];

    for (int t = 0; t < 22; ++t) {
        int cur = t & 1;
        char* Ab = smem + cur * 16384;
        char* Bb = smem + 32768 + cur * 8192;
        if (t < 21) {
            int ns = cur ^ 1;
#pragma unroll
            for (int i = 0; i < 4; ++i)
                dma16(srcA[i] + (size_t)(t + 1) * 256, dstA[i] + ns * 16384);
#pragma unroll
            for (int i = 0; i < 2; ++i)
                dma16(srcB[i] + (size_t)(t + 1) * 512, dstB[i] + ns * 8192);
        }
#pragma unroll
        for (int kk = 0; kk < 4; ++kk) {
            int bo = r16 * 512 + kk * 128 + kg * 32;
            int sw = (r16 & 15) << 4;
            float4 b0 = *(float4*)(Bb + (bo ^ sw));
            float4 b1 = *(float4*)(Bb + ((bo + 16) ^ sw));
            uint4 bu = make_uint4(pack_trunc(b0.x, b0.y), pack_trunc(b0.z, b0.w),
                                  pack_trunc(b1.x, b1.y), pack_trunc(b1.z, b1.w));
            short8 B = __builtin_bit_cast(short8, bu);
            int ar = w * 16 + r16;
            short8 A = *(short8*)(Ab + ((ar * 256 + kk * 64 + kg * 16) ^ ((ar & 15) << 4)));
            acc = __builtin_amdgcn_mfma_f32_16x16x32_bf16(A, B, acc, 0, 0, 0);
        }
        __syncthreads();
    }
#pragma unroll
    for (int j = 0; j < 4; ++j) {
        int tr = w * 16 + kg * 4 + j;
        int pos = mt * 64 + tr;
        if (pos < cnt)
            out[(size_t)tok[tr] * H_ + h0 + r16] = acc[j] * sd;
    }
}

extern "C" void kernel_launch(void* const* d_in, const int* in_sizes, int n_in,
                              void* d_out, int out_size, void* d_ws, size_t ws_size,
                              hipStream_t stream) {
    const float* x    = (const float*)d_in[0];
    const int*   eidx = (const int*)d_in[1];
    const float* wgu  = (const float*)d_in[2];   // fp8 values stored as f32
    const float* sgu  = (const float*)d_in[3];
    const float* wd   = (const float*)d_in[4];   // fp8 values stored as f32
    const float* sd   = (const float*)d_in[5];
    float* out = (float*)d_out;

    char* ws = (char*)d_ws;
    int* counts = (int*)ws;                                  // 32 B
    int* bucket = (int*)(ws + 1024);                         // 16 KB
    __hip_bfloat16* hbuf = (__hip_bfloat16*)(ws + 32768);    // 2.88 MB

    routek<<<1, 512, 0, stream>>>(eidx, counts, bucket);
    gemm1<<<dim3(E_ * 2, I_ / 32), 256, 0, stream>>>(x, wgu, sgu, counts, bucket, hbuf);
    gemm2<<<dim3(E_ * 2, H_ / 16), 256, 0, stream>>>(hbuf, wd, sd, counts, bucket, out);
}

// Round 7
// 121.726 us; speedup vs baseline: 3.3690x; 1.0183x over previous
//
#include <hip/hip_runtime.h>
#include <hip/hip_bf16.h>
#include <stdint.h>

#define E_ 8
#define H_ 1024
#define I_ 2816
#define T_ 512

typedef __attribute__((ext_vector_type(4))) float f32x4;
typedef __attribute__((ext_vector_type(8))) short short8;

typedef __attribute__((address_space(1))) const unsigned GAS;
typedef __attribute__((address_space(3))) unsigned LAS;

__device__ __forceinline__ void dma16(const void* g, void* l) {
    __builtin_amdgcn_global_load_lds((GAS*)g, (LAS*)l, 16, 0, 0);
}
__device__ __forceinline__ unsigned short f2bf(float f) {   // RNE
    return __builtin_bit_cast(unsigned short, __float2bfloat16(f));
}
__device__ __forceinline__ uint32_t pack_rne(float lo, float hi) {
    return (uint32_t)f2bf(lo) | ((uint32_t)f2bf(hi) << 16);
}
// weights hold exact e4m3 values -> bf16 truncation is exact
__device__ __forceinline__ uint32_t pack_trunc(float lo, float hi) {
    return (__builtin_bit_cast(uint32_t, hi) & 0xFFFF0000u) |
           (__builtin_bit_cast(uint32_t, lo) >> 16);
}

#define VM6() asm volatile("s_waitcnt vmcnt(6)" ::: "memory")
#define VM0() asm volatile("s_waitcnt vmcnt(0)" ::: "memory")

// ---- routing + x->bf16 conversion (fused) ----
__global__ __launch_bounds__(256) void route_cvt(const float* __restrict__ x,
                                                 const int* __restrict__ idx,
                                                 int* __restrict__ counts,
                                                 int* __restrict__ bucket,
                                                 unsigned short* __restrict__ xg) {
    int tid = threadIdx.x;
    if (blockIdx.x == 0) {
        if (tid < E_) counts[tid] = 0;
        for (int i = tid; i < E_ * T_; i += 256) bucket[i] = 0;
        __syncthreads();
#pragma unroll
        for (int k = 0; k < 2; ++k) {
            int t = tid + k * 256;
            int e = idx[t];
            int pos = atomicAdd(counts + e, 1);
            bucket[e * T_ + pos] = t;
        }
    }
    int unit = blockIdx.x * 256 + tid;           // 65536 units of 8 elems
    const float* xp = x + (size_t)unit * 8;
    float4 a = *(const float4*)xp, b = *(const float4*)(xp + 4);
    uint4 o = make_uint4(pack_rne(a.x, a.y), pack_rne(a.z, a.w),
                         pack_rne(b.x, b.y), pack_rne(b.z, b.w));
    *(uint4*)(xg + (size_t)unit * 8) = o;
}

// ---- GEMM1: 64 tok x 32 feat, BK=64, 16 steps, depth-3 counted-vmcnt DMA ----
// LDS: A bf16 3x8KB @0 ; B f32 3x16KB @24KB ; tok @72KB
__global__ __launch_bounds__(256) void gemm1(const unsigned short* __restrict__ xg,
                                             const float* __restrict__ wgu,
                                             const float* __restrict__ sgu_p,
                                             const int* __restrict__ counts,
                                             const int* __restrict__ bucket,
                                             __hip_bfloat16* __restrict__ hbuf) {
    int e = blockIdx.x >> 1, mt = blockIdx.x & 1;
    int cnt = counts[e];
    if (mt * 64 >= cnt) return;
    int f0 = blockIdx.y * 32;

    __shared__ __align__(16) char smem[72 * 1024 + 256];
    int* tok = (int*)(smem + 72 * 1024);
    int tid = threadIdx.x, w = tid >> 6, lane = tid & 63;
    int r16 = lane & 15, kg = lane >> 4;

    float sgu = sgu_p[0];
    asm volatile("" :: "v"(sgu));                 // materialize before DMA issue

    if (tid < 64) tok[tid] = bucket[e * T_ + mt * 64 + tid];
    __syncthreads();                              // tok visible, vmcnt drained

    // A: 2 chunks/wave (64 rows x 8 slots of 16B), pre-swizzled source
    const char* xb = (const char*)xg;
    const char* srcA[2]; char* dstA[2];
#pragma unroll
    for (int i = 0; i < 2; ++i) {
        int U = (w * 2 + i) * 64 + lane;
        int row = U >> 3, sl = U & 7;
        srcA[i] = xb + (size_t)tok[row] * 2048 + (size_t)((sl ^ (row & 7)) * 16);
        dstA[i] = smem + (w * 2 + i) * 1024;
    }
    // B: 4 chunks/wave (64 rows [32 gate + 32 up] x 16 slots)
    const char* wg_e = (const char*)(wgu + (size_t)e * 2 * (size_t)I_ * H_);
    const char* srcB[4]; char* dstB[4];
#pragma unroll
    for (int i = 0; i < 4; ++i) {
        int U = (w * 4 + i) * 64 + lane;
        int row = U >> 4, sl = U & 15;
        int wr = (row < 32) ? (f0 + row) : (I_ + f0 + row - 32);
        srcB[i] = wg_e + (size_t)wr * 4096 + (size_t)((sl ^ (row & 15)) * 16);
        dstB[i] = smem + 24 * 1024 + (w * 4 + i) * 1024;
    }

#define G1_ISSUE(s, buf)                                                     \
    do {                                                                     \
        _Pragma("unroll")                                                    \
        for (int i = 0; i < 2; ++i) dma16(srcA[i] + (size_t)(s) * 128, dstA[i] + (buf) * 8192);  \
        _Pragma("unroll")                                                    \
        for (int i = 0; i < 4; ++i) dma16(srcB[i] + (size_t)(s) * 256, dstB[i] + (buf) * 16384); \
    } while (0)

    G1_ISSUE(0, 0);
    G1_ISSUE(1, 1);

    f32x4 acc[4];
#pragma unroll
    for (int m = 0; m < 4; ++m) acc[m] = (f32x4){0, 0, 0, 0};

    for (int t = 0; t < 16; ++t) {
        VM6();                                    // step t landed; t+1 in flight
        __builtin_amdgcn_s_barrier();
        int tp = (t + 2 < 16) ? t + 2 : 15;       // clamped tail keeps counts uniform
        G1_ISSUE(tp, (t + 2) % 3);
        const char* Ab = smem + (t % 3) * 8192;
        const char* Bb = smem + 24 * 1024 + (t % 3) * 16384;
#pragma unroll
        for (int kk = 0; kk < 2; ++kk) {
            int brow = w * 16 + r16;
            int bo = brow * 256 + kk * 128 + kg * 32;
            int sw = r16 << 4;
            float4 b0 = *(float4*)(Bb + (bo ^ sw));
            float4 b1 = *(float4*)(Bb + ((bo + 16) ^ sw));
            uint4 bu = make_uint4(pack_trunc(b0.x, b0.y), pack_trunc(b0.z, b0.w),
                                  pack_trunc(b1.x, b1.y), pack_trunc(b1.z, b1.w));
            short8 B = __builtin_bit_cast(short8, bu);
#pragma unroll
            for (int m = 0; m < 4; ++m) {
                int ar = m * 16 + r16;
                short8 A = *(short8*)(Ab + ((ar * 128 + kk * 64 + kg * 16) ^ ((ar & 7) << 4)));
                acc[m] = __builtin_amdgcn_mfma_f32_16x16x32_bf16(A, B, acc[m], 0, 0, 0);
            }
        }
    }
    VM0();
    __syncthreads();                              // LDS free for epilogue reuse

    // epilogue: waves 2,3 (up) export u*s; waves 0,1 (gate) fuse silu
    float* ex = (float*)smem;
    if (w >= 2) {
        float* dst = ex + (w - 2) * 1024;
#pragma unroll
        for (int m = 0; m < 4; ++m)
#pragma unroll
            for (int j = 0; j < 4; ++j)
                dst[(m * 16 + kg * 4 + j) * 16 + r16] = acc[m][j] * sgu;
    }
    __syncthreads();
    if (w < 2) {
        const float* src = ex + w * 1024;
#pragma unroll
        for (int m = 0; m < 4; ++m)
#pragma unroll
            for (int j = 0; j < 4; ++j) {
                int tr = m * 16 + kg * 4 + j;
                int pos = mt * 64 + tr;
                if (pos < cnt) {
                    float g = acc[m][j] * sgu;
                    float u = src[tr * 16 + r16];
                    float hv = (g / (1.f + __expf(-g))) * u;
                    hbuf[(size_t)tok[tr] * I_ + f0 + w * 16 + r16] = __float2bfloat16(hv);
                }
            }
    }
}

// ---- GEMM2: 64 tok x 16 hcols, BK=128, 22 steps, same template ----
// LDS: A bf16 3x16KB @0 ; B f32 3x8KB @48KB ; tok @72KB
__global__ __launch_bounds__(256) void gemm2(const __hip_bfloat16* __restrict__ hbuf,
                                             const float* __restrict__ wd,
                                             const float* __restrict__ sd_p,
                                             const int* __restrict__ counts,
                                             const int* __restrict__ bucket,
                                             float* __restrict__ out) {
    int e = blockIdx.x >> 1, mt = blockIdx.x & 1;
    int cnt = counts[e];
    if (mt * 64 >= cnt) return;
    int h0 = blockIdx.y * 16;

    __shared__ __align__(16) char smem[72 * 1024 + 256];
    int* tok = (int*)(smem + 72 * 1024);
    int tid = threadIdx.x, w = tid >> 6, lane = tid & 63;
    int r16 = lane & 15, kg = lane >> 4;

    float sd = sd_p[0];
    asm volatile("" :: "v"(sd));

    if (tid < 64) tok[tid] = bucket[e * T_ + mt * 64 + tid];
    __syncthreads();

    // A: 4 chunks/wave (64 rows x 16 slots)
    const char* hb = (const char*)hbuf;
    const char* srcA[4]; char* dstA[4];
#pragma unroll
    for (int i = 0; i < 4; ++i) {
        int U = (w * 4 + i) * 64 + lane;
        int row = U >> 4, sl = U & 15;
        srcA[i] = hb + (size_t)tok[row] * (I_ * 2) + (size_t)((sl ^ (row & 15)) * 16);
        dstA[i] = smem + (w * 4 + i) * 1024;
    }
    // B: 2 chunks/wave (16 rows x 32 slots)
    const char* wd_e = (const char*)(wd + (size_t)e * (size_t)H_ * I_);
    const char* srcB[2]; char* dstB[2];
#pragma unroll
    for (int i = 0; i < 2; ++i) {
        int U = (w * 2 + i) * 64 + lane;
        int row = U >> 5, sl = U & 31;
        srcB[i] = wd_e + (size_t)(h0 + row) * ((size_t)I_ * 4) + (size_t)((sl ^ (row & 15)) * 16);
        dstB[i] = smem + 48 * 1024 + (w * 2 + i) * 1024;
    }

#define G2_ISSUE(s, buf)                                                     \
    do {                                                                     \
        _Pragma("unroll")                                                    \
        for (int i = 0; i < 4; ++i) dma16(srcA[i] + (size_t)(s) * 256, dstA[i] + (buf) * 16384); \
        _Pragma("unroll")                                                    \
        for (int i = 0; i < 2; ++i) dma16(srcB[i] + (size_t)(s) * 512, dstB[i] + (buf) * 8192);  \
    } while (0)

    G2_ISSUE(0, 0);
    G2_ISSUE(1, 1);

    f32x4 acc = (f32x4){0, 0, 0, 0};

    for (int t = 0; t < 22; ++t) {
        VM6();
        __builtin_amdgcn_s_barrier();
        int tp = (t + 2 < 22) ? t + 2 : 21;
        G2_ISSUE(tp, (t + 2) % 3);
        const char* Ab = smem + (t % 3) * 16384;
        const char* Bb = smem + 48 * 1024 + (t % 3) * 8192;
#pragma unroll
        for (int kk = 0; kk < 4; ++kk) {
            int bo = r16 * 512 + kk * 128 + kg * 32;
            int sw = r16 << 4;
            float4 b0 = *(float4*)(Bb + (bo ^ sw));
            float4 b1 = *(float4*)(Bb + ((bo + 16) ^ sw));
            uint4 bu = make_uint4(pack_trunc(b0.x, b0.y), pack_trunc(b0.z, b0.w),
                                  pack_trunc(b1.x, b1.y), pack_trunc(b1.z, b1.w));
            short8 B = __builtin_bit_cast(short8, bu);
            int ar = w * 16 + r16;
            short8 A = *(short8*)(Ab + ((ar * 256 + kk * 64 + kg * 16) ^ ((ar & 15) << 4)));
            acc = __builtin_amdgcn_mfma_f32_16x16x32_bf16(A, B, acc, 0, 0, 0);
        }
    }
    VM0();

#pragma unroll
    for (int j = 0; j < 4; ++j) {
        int tr = w * 16 + kg * 4 + j;
        int pos = mt * 64 + tr;
        if (pos < cnt)
            out[(size_t)tok[tr] * H_ + h0 + r16] = acc[j] * sd;
    }
}

extern "C" void kernel_launch(void* const* d_in, const int* in_sizes, int n_in,
                              void* d_out, int out_size, void* d_ws, size_t ws_size,
                              hipStream_t stream) {
    const float* x    = (const float*)d_in[0];
    const int*   eidx = (const int*)d_in[1];
    const float* wgu  = (const float*)d_in[2];   // fp8 values stored as f32
    const float* sgu  = (const float*)d_in[3];
    const float* wd   = (const float*)d_in[4];   // fp8 values stored as f32
    const float* sd   = (const float*)d_in[5];
    float* out = (float*)d_out;

    char* ws = (char*)d_ws;
    int* counts = (int*)ws;                                   // 32 B
    int* bucket = (int*)(ws + 1024);                          // 16 KB
    unsigned short* xg = (unsigned short*)(ws + 32768);       // 1 MB bf16 x
    __hip_bfloat16* hbuf = (__hip_bfloat16*)(ws + 1114112);   // 2.88 MB

    route_cvt<<<256, 256, 0, stream>>>(x, eidx, counts, bucket, xg);
    gemm1<<<dim3(E_ * 2, I_ / 32), 256, 0, stream>>>(xg, wgu, sgu, counts, bucket, hbuf);
    gemm2<<<dim3(E_ * 2, H_ / 16), 256, 0, stream>>>(hbuf, wd, sd, counts, bucket, out);
}